// Round 1
// baseline (3633.382 us; speedup 1.0000x reference)
//
#include <hip/hip_runtime.h>

#define N_NODES 100000
#define D_IN 128
#define D_OUT 256            // OUT_CH * HEADS
#define NBLK 200             // coarse-pass blocks
#define NBKT 1024            // bucket array size (782 used)
#define BSH  7               // bucket = dst >> 7  (128 nodes / bucket)
#define BNODES 128
#define NBUCKETS ((N_NODES + BNODES - 1) / BNODES)   // 782

__device__ inline unsigned short f2bf_rne(float f) {
    unsigned u = __float_as_uint(f);
    u += 0x7fffu + ((u >> 16) & 1u);
    return (unsigned short)(u >> 16);
}

// ---------------------------------------------------------------------------
// x (fp32) -> xb (bf16 as ushort)
// ---------------------------------------------------------------------------
__global__ __launch_bounds__(256) void convert_kernel(
    const float* __restrict__ x, ushort* __restrict__ xb, int n4)
{
    int i = blockIdx.x * 256 + threadIdx.x;
    if (i < n4) {
        float4 v = ((const float4*)x)[i];
        ushort4 r;
        r.x = f2bf_rne(v.x); r.y = f2bf_rne(v.y);
        r.z = f2bf_rne(v.z); r.w = f2bf_rne(v.w);
        ((ushort4*)xb)[i] = r;
    }
}

// ---------------------------------------------------------------------------
// Coarse pass 1: per-block LDS histogram of buckets
// ---------------------------------------------------------------------------
__global__ __launch_bounds__(256) void binA_hist(
    const int* __restrict__ dst, int* __restrict__ blockHist, int E, int chunk)
{
    __shared__ int h[NBKT];
    int b = blockIdx.x, t = threadIdx.x;
    for (int i = t; i < NBKT; i += 256) h[i] = 0;
    __syncthreads();
    int e0 = b * chunk, e1 = min(e0 + chunk, E);
    for (int e = e0 + t; e < e1; e += 256)
        atomicAdd(&h[dst[e] >> BSH], 1);
    __syncthreads();
    for (int i = t; i < NBKT; i += 256)
        blockHist[b * NBKT + i] = h[i];
}

// ---------------------------------------------------------------------------
// Coarse pass 2a: per-bucket exclusive scan over blocks, in place;
// bucketTotal[bucket] = column sum.
// ---------------------------------------------------------------------------
__global__ __launch_bounds__(256) void binA_scan(
    int* __restrict__ blockHist, int* __restrict__ bucketTotal)
{
    __shared__ int wsum[4];
    int bucket = blockIdx.x;
    int t = threadIdx.x, lane = t & 63, w = t >> 6;
    int v = (t < NBLK) ? blockHist[t * NBKT + bucket] : 0;
    int s = v;
    #pragma unroll
    for (int d = 1; d < 64; d <<= 1) {
        int u = __shfl_up(s, d);
        if (lane >= d) s += u;
    }
    if (lane == 63) wsum[w] = s;
    __syncthreads();
    int wo = 0;
    for (int j = 0; j < w; j++) wo += wsum[j];
    if (t < NBLK) blockHist[t * NBKT + bucket] = wo + s - v;
    if (t == 255) {
        int tot = 0;
        for (int j = 0; j < 4; j++) tot += wsum[j];
        bucketTotal[bucket] = tot;
    }
}

// ---------------------------------------------------------------------------
// Coarse pass 2b: exclusive scan of bucketTotal[1024] -> bucketBase[1024]
// (4 entries per thread)
// ---------------------------------------------------------------------------
__global__ __launch_bounds__(256) void binA_scanbase(
    const int* __restrict__ bucketTotal, int* __restrict__ bucketBase)
{
    __shared__ int wsum[4];
    int t = threadIdx.x, lane = t & 63, w = t >> 6;
    int i0 = t * 4;
    int a0 = bucketTotal[i0];
    int a1 = bucketTotal[i0 + 1];
    int a2 = bucketTotal[i0 + 2];
    int a3 = bucketTotal[i0 + 3];
    int v = a0 + a1 + a2 + a3;
    int s = v;
    #pragma unroll
    for (int d = 1; d < 64; d <<= 1) {
        int u = __shfl_up(s, d);
        if (lane >= d) s += u;
    }
    if (lane == 63) wsum[w] = s;
    __syncthreads();
    int wo = 0;
    for (int j = 0; j < w; j++) wo += wsum[j];
    int excl = wo + s - v;
    bucketBase[i0]     = excl;
    bucketBase[i0 + 1] = excl + a0;
    bucketBase[i0 + 2] = excl + a0 + a1;
    bucketBase[i0 + 3] = excl + a0 + a1 + a2;
}

// ---------------------------------------------------------------------------
// Coarse pass 3: scatter packed (dstLocal<<17 | src) into bucket regions.
// ---------------------------------------------------------------------------
__global__ __launch_bounds__(256) void binA_scatter(
    const int* __restrict__ src, const int* __restrict__ dst,
    const int* __restrict__ blockHist, const int* __restrict__ bucketBase,
    unsigned* __restrict__ pairs, int E, int chunk)
{
    __shared__ int offs[NBKT];
    int b = blockIdx.x, t = threadIdx.x;
    for (int i = t; i < NBKT; i += 256)
        offs[i] = bucketBase[i] + blockHist[b * NBKT + i];
    __syncthreads();
    int e0 = b * chunk, e1 = min(e0 + chunk, E);
    for (int e = e0 + t; e < e1; e += 256) {
        int d = dst[e];
        int bin = d >> BSH;
        int pos = atomicAdd(&offs[bin], 1);
        pairs[pos] = ((unsigned)(d & (BNODES - 1)) << 17) | (unsigned)src[e];
    }
}

// ---------------------------------------------------------------------------
// Fused bucket kernel: LDS fp32 accumulator for 128 nodes x 128 dims,
// edge-streamed ds_add_f32 aggregation (no fine sort, no CSR), then
// mean + residual + linear, all in one block.
// LDS layout de-interleaved: dim 2i -> slot i, dim 2i+1 -> slot 64+i
// so per-edge atomics are lane-stride 4B (2-way bank alias = free).
// ---------------------------------------------------------------------------
template <bool USE_BF16>
__global__ __launch_bounds__(512, 4) void fused_bucket(
    const float* __restrict__ x,
    const ushort* __restrict__ xb,
    const unsigned* __restrict__ pairs,
    const int* __restrict__ bucketBase,
    const float* __restrict__ W,
    const float* __restrict__ b,
    float* __restrict__ out)
{
    __shared__ __align__(16) float agg[BNODES * D_IN];   // 64 KB
    __shared__ int cnt[BNODES];

    const int t    = threadIdx.x;
    const int lane = t & 63;
    const int wid  = t >> 6;            // 0..7
    const int bkt  = blockIdx.x;
    const int n0   = bkt << BSH;

    // --- zero accumulators ---
    for (int i = t; i < BNODES * D_IN / 4; i += 512)
        ((float4*)agg)[i] = make_float4(0.f, 0.f, 0.f, 0.f);
    if (t < BNODES) cnt[t] = 0;
    __syncthreads();

    // --- edge accumulate ---
    const int e0 = bucketBase[bkt], e1 = bucketBase[bkt + 1];
    for (int base = e0 + (wid << 6); base < e1; base += 512) {
        int m = e1 - base; if (m > 64) m = 64;
        unsigned p = (lane < m) ? pairs[base + lane] : 0u;
        if (lane < m) atomicAdd(&cnt[p >> 17], 1);
        #pragma unroll 4
        for (int j = 0; j < m; ++j) {
            unsigned pj = (unsigned)__builtin_amdgcn_readlane((int)p, j);
            int dl = (int)(pj >> 17);
            int s  = (int)(pj & 0x1FFFFu);
            float a, c;
            if (USE_BF16) {
                ushort2 u = ((const ushort2*)(xb + (size_t)s * D_IN))[lane];
                a = __uint_as_float((unsigned)u.x << 16);
                c = __uint_as_float((unsigned)u.y << 16);
            } else {
                float2 v = ((const float2*)(x + (size_t)s * D_IN))[lane];
                a = v.x; c = v.y;
            }
            atomicAdd(&agg[dl * D_IN + lane], a);
            atomicAdd(&agg[dl * D_IN + 64 + lane], c);
        }
    }
    __syncthreads();

    // --- h = x + agg/deg (in place, same de-interleaved layout) ---
    for (int idx = t; idx < BNODES * 64; idx += 512) {
        int nl = idx >> 6, i = idx & 63;
        int node = n0 + nl;
        float inv = 1.0f / ((float)cnt[nl] + 1e-8f);
        float2 xv = make_float2(0.f, 0.f);
        if (node < N_NODES)
            xv = ((const float2*)(x + (size_t)node * D_IN))[i];
        agg[nl * D_IN + i]      = xv.x + agg[nl * D_IN + i]      * inv;
        agg[nl * D_IN + 64 + i] = xv.y + agg[nl * D_IN + 64 + i] * inv;
    }
    __syncthreads();

    // --- linear: thread owns cols (c0, c0+1) for 32 nodes ---
    // slot q maps to dim k(q) = (q<64) ? 2q : 2(q-64)+1 ; consecutive q -> k += 2
    const int ch = t & 127;             // 0..127
    const int g  = t >> 7;              // 0..3 -> nodes g*32 .. g*32+31
    const int c0 = ch * 2;

    float2 acc[32];
    #pragma unroll
    for (int i = 0; i < 32; i++) acc[i] = make_float2(0.f, 0.f);

    const float* hbase = agg + g * 32 * D_IN;
    for (int qb = 0; qb < D_IN; qb += 4) {
        int kb = (qb < 64) ? (qb << 1) : (((qb - 64) << 1) | 1);
        float2 w0 = *(const float2*)(W + (size_t)(kb    ) * D_OUT + c0);
        float2 w1 = *(const float2*)(W + (size_t)(kb + 2) * D_OUT + c0);
        float2 w2 = *(const float2*)(W + (size_t)(kb + 4) * D_OUT + c0);
        float2 w3 = *(const float2*)(W + (size_t)(kb + 6) * D_OUT + c0);
        #pragma unroll
        for (int i = 0; i < 32; i++) {
            float4 hv = *(const float4*)(hbase + i * D_IN + qb);
            acc[i].x += hv.x * w0.x + hv.y * w1.x + hv.z * w2.x + hv.w * w3.x;
            acc[i].y += hv.x * w0.y + hv.y * w1.y + hv.z * w2.y + hv.w * w3.y;
        }
    }

    float b0 = b[c0], b1 = b[c0 + 1];
    #pragma unroll
    for (int i = 0; i < 32; i++) {
        int node = n0 + g * 32 + i;
        if (node < N_NODES)
            ((float2*)(out + (size_t)node * D_OUT))[ch] =
                make_float2(acc[i].x + b0, acc[i].y + b1);
    }
}

extern "C" void kernel_launch(void* const* d_in, const int* in_sizes, int n_in,
                              void* d_out, int out_size, void* d_ws, size_t ws_size,
                              hipStream_t stream)
{
    const float* x  = (const float*)d_in[0];
    const int*   ei = (const int*)d_in[1];   // [2,E] int32: row0=src, row1=dst
    const float* W  = (const float*)d_in[2];
    const float* b  = (const float*)d_in[3];
    float*       out = (float*)d_out;

    const int E = in_sizes[1] / 2;
    const int* src = ei;
    const int* dst = ei + E;
    const int chunk = (E + NBLK - 1) / NBLK;

    const size_t xb_bytes = (size_t)N_NODES * D_IN * 2;     // 25.6 MB
    const size_t pairs_b  = (size_t)E * 4;                  // 12.8 MB
    const size_t bh_b     = (size_t)NBLK * NBKT * 4;        // 819.2 KB
    const size_t small_b  = (size_t)NBKT * 4;               // 4 KB each
    const size_t need_bf16 = xb_bytes + pairs_b + bh_b + 2 * small_b;
    const bool use_bf16 = (ws_size >= need_bf16);

    char* p = (char*)d_ws;
    ushort* xb = nullptr;
    if (use_bf16) { xb = (ushort*)p; p += xb_bytes; }
    unsigned* pairs  = (unsigned*)p;  p += pairs_b;
    int* blockHist   = (int*)p;       p += bh_b;
    int* bucketTotal = (int*)p;       p += small_b;
    int* bucketBase  = (int*)p;

    if (use_bf16) {
        int n4 = N_NODES * D_IN / 4;
        convert_kernel<<<dim3((n4 + 255) / 256), dim3(256), 0, stream>>>(x, xb, n4);
    }

    binA_hist    <<<dim3(NBLK), dim3(256), 0, stream>>>(dst, blockHist, E, chunk);
    binA_scan    <<<dim3(NBKT), dim3(256), 0, stream>>>(blockHist, bucketTotal);
    binA_scanbase<<<dim3(1),    dim3(256), 0, stream>>>(bucketTotal, bucketBase);
    binA_scatter <<<dim3(NBLK), dim3(256), 0, stream>>>(
        src, dst, blockHist, bucketBase, pairs, E, chunk);

    if (use_bf16)
        fused_bucket<true><<<dim3(NBUCKETS), dim3(512), 0, stream>>>(
            x, xb, pairs, bucketBase, W, b, out);
    else
        fused_bucket<false><<<dim3(NBUCKETS), dim3(512), 0, stream>>>(
            x, xb, pairs, bucketBase, W, b, out);
}

// Round 3
// 2979.231 us; speedup vs baseline: 1.2196x; 1.2196x over previous
//
#include <hip/hip_runtime.h>

#define N_NODES 100000
#define D_IN 128
#define D_OUT 256            // OUT_CH * HEADS
#define NBLK 256             // coarse-pass blocks
#define NBKT 1024            // bucket array size (782 used)
#define BSH  7               // bucket = dst >> 7  (128 nodes / bucket)
#define BNODES 128
#define NBUCKETS ((N_NODES + BNODES - 1) / BNODES)   // 782

__device__ inline unsigned short f2bf_rne(float f) {
    unsigned u = __float_as_uint(f);
    u += 0x7fffu + ((u >> 16) & 1u);
    return (unsigned short)(u >> 16);
}

// ---------------------------------------------------------------------------
// x (fp32) -> xb (bf16 as ushort)
// ---------------------------------------------------------------------------
__global__ __launch_bounds__(256) void convert_kernel(
    const float* __restrict__ x, ushort* __restrict__ xb, int n4)
{
    int i = blockIdx.x * 256 + threadIdx.x;
    if (i < n4) {
        float4 v = ((const float4*)x)[i];
        ushort4 r;
        r.x = f2bf_rne(v.x); r.y = f2bf_rne(v.y);
        r.z = f2bf_rne(v.z); r.w = f2bf_rne(v.w);
        ((ushort4*)xb)[i] = r;
    }
}

// ---------------------------------------------------------------------------
// Coarse pass 1: per-block LDS histogram of buckets
// ---------------------------------------------------------------------------
__global__ __launch_bounds__(256) void binA_hist(
    const int* __restrict__ dst, int* __restrict__ blockHist, int E, int chunk)
{
    __shared__ int h[NBKT];
    int b = blockIdx.x, t = threadIdx.x;
    for (int i = t; i < NBKT; i += 256) h[i] = 0;
    __syncthreads();
    int e0 = b * chunk, e1 = min(e0 + chunk, E);
    for (int e = e0 + t; e < e1; e += 256)
        atomicAdd(&h[dst[e] >> BSH], 1);
    __syncthreads();
    for (int i = t; i < NBKT; i += 256)
        blockHist[b * NBKT + i] = h[i];
}

// ---------------------------------------------------------------------------
// Coarse pass 2a: per-bucket exclusive scan over blocks, in place;
// bucketTotal[bucket] = column sum.  (NBLK must be <= 256)
// ---------------------------------------------------------------------------
__global__ __launch_bounds__(256) void binA_scan(
    int* __restrict__ blockHist, int* __restrict__ bucketTotal)
{
    __shared__ int wsum[4];
    int bucket = blockIdx.x;
    int t = threadIdx.x, lane = t & 63, w = t >> 6;
    int v = (t < NBLK) ? blockHist[t * NBKT + bucket] : 0;
    int s = v;
    #pragma unroll
    for (int d = 1; d < 64; d <<= 1) {
        int u = __shfl_up(s, d);
        if (lane >= d) s += u;
    }
    if (lane == 63) wsum[w] = s;
    __syncthreads();
    int wo = 0;
    for (int j = 0; j < w; j++) wo += wsum[j];
    if (t < NBLK) blockHist[t * NBKT + bucket] = wo + s - v;
    if (t == 255) {
        int tot = 0;
        for (int j = 0; j < 4; j++) tot += wsum[j];
        bucketTotal[bucket] = tot;
    }
}

// ---------------------------------------------------------------------------
// Coarse pass 2b: exclusive scan of bucketTotal[1024] -> bucketBase[1024]
// (4 entries per thread)
// ---------------------------------------------------------------------------
__global__ __launch_bounds__(256) void binA_scanbase(
    const int* __restrict__ bucketTotal, int* __restrict__ bucketBase)
{
    __shared__ int wsum[4];
    int t = threadIdx.x, lane = t & 63, w = t >> 6;
    int i0 = t * 4;
    int a0 = bucketTotal[i0];
    int a1 = bucketTotal[i0 + 1];
    int a2 = bucketTotal[i0 + 2];
    int a3 = bucketTotal[i0 + 3];
    int v = a0 + a1 + a2 + a3;
    int s = v;
    #pragma unroll
    for (int d = 1; d < 64; d <<= 1) {
        int u = __shfl_up(s, d);
        if (lane >= d) s += u;
    }
    if (lane == 63) wsum[w] = s;
    __syncthreads();
    int wo = 0;
    for (int j = 0; j < w; j++) wo += wsum[j];
    int excl = wo + s - v;
    bucketBase[i0]     = excl;
    bucketBase[i0 + 1] = excl + a0;
    bucketBase[i0 + 2] = excl + a0 + a1;
    bucketBase[i0 + 3] = excl + a0 + a1 + a2;
}

// ---------------------------------------------------------------------------
// Coarse pass 3: scatter packed (dstLocal<<17 | src) into bucket regions.
// ---------------------------------------------------------------------------
__global__ __launch_bounds__(256) void binA_scatter(
    const int* __restrict__ src, const int* __restrict__ dst,
    const int* __restrict__ blockHist, const int* __restrict__ bucketBase,
    unsigned* __restrict__ pairs, int E, int chunk)
{
    __shared__ int offs[NBKT];
    int b = blockIdx.x, t = threadIdx.x;
    for (int i = t; i < NBKT; i += 256)
        offs[i] = bucketBase[i] + blockHist[b * NBKT + i];
    __syncthreads();
    int e0 = b * chunk, e1 = min(e0 + chunk, E);
    for (int e = e0 + t; e < e1; e += 256) {
        int d = dst[e];
        int bin = d >> BSH;
        int pos = atomicAdd(&offs[bin], 1);
        pairs[pos] = ((unsigned)(d & (BNODES - 1)) << 17) | (unsigned)src[e];
    }
}

// ---------------------------------------------------------------------------
// Fused bucket kernel: LDS fp32 accumulator for 128 nodes x 128 dims,
// edge-streamed ds_add_f32 aggregation, then mean + residual + linear.
// LDS layout de-interleaved: dim 2i -> slot i, dim 2i+1 -> slot 64+i.
// Matmul: 2 passes x (4 groups x 16 nodes), thread owns 2 cols x 16 nodes,
// acc[16] float2 (32 VGPR, fully unrollable — round-0-proven shape).
// ---------------------------------------------------------------------------
template <bool USE_BF16>
__global__ __launch_bounds__(512, 4) void fused_bucket(
    const float* __restrict__ x,
    const ushort* __restrict__ xb,
    const unsigned* __restrict__ pairs,
    const int* __restrict__ bucketBase,
    const float* __restrict__ W,
    const float* __restrict__ b,
    float* __restrict__ out)
{
    __shared__ __align__(16) float agg[BNODES * D_IN];   // 64 KB
    __shared__ int cnt[BNODES];

    const int t    = threadIdx.x;
    const int lane = t & 63;
    const int wid  = t >> 6;            // 0..7
    const int bkt  = blockIdx.x;
    const int n0   = bkt << BSH;

    // --- zero accumulators ---
    for (int i = t; i < BNODES * D_IN / 4; i += 512)
        ((float4*)agg)[i] = make_float4(0.f, 0.f, 0.f, 0.f);
    if (t < BNODES) cnt[t] = 0;
    __syncthreads();

    // --- edge accumulate ---
    const int e0 = bucketBase[bkt], e1 = bucketBase[bkt + 1];
    for (int base = e0 + (wid << 6); base < e1; base += 512) {
        int m = e1 - base; if (m > 64) m = 64;
        unsigned p = (lane < m) ? pairs[base + lane] : 0u;
        if (lane < m) atomicAdd(&cnt[p >> 17], 1);
        #pragma unroll 4
        for (int j = 0; j < m; ++j) {
            unsigned pj = (unsigned)__builtin_amdgcn_readlane((int)p, j);
            int dl = (int)(pj >> 17);
            int s  = (int)(pj & 0x1FFFFu);
            float a, c;
            if (USE_BF16) {
                ushort2 u = ((const ushort2*)(xb + (size_t)s * D_IN))[lane];
                a = __uint_as_float((unsigned)u.x << 16);
                c = __uint_as_float((unsigned)u.y << 16);
            } else {
                float2 v = ((const float2*)(x + (size_t)s * D_IN))[lane];
                a = v.x; c = v.y;
            }
            atomicAdd(&agg[dl * D_IN + lane], a);
            atomicAdd(&agg[dl * D_IN + 64 + lane], c);
        }
    }
    __syncthreads();

    // --- h = x + agg/deg (in place, same de-interleaved layout) ---
    for (int idx = t; idx < BNODES * 64; idx += 512) {
        int nl = idx >> 6, i = idx & 63;
        int node = n0 + nl;
        float inv = 1.0f / ((float)cnt[nl] + 1e-8f);
        float2 xv = make_float2(0.f, 0.f);
        if (node < N_NODES)
            xv = ((const float2*)(x + (size_t)node * D_IN))[i];
        agg[nl * D_IN + i]      = xv.x + agg[nl * D_IN + i]      * inv;
        agg[nl * D_IN + 64 + i] = xv.y + agg[nl * D_IN + 64 + i] * inv;
    }
    __syncthreads();

    // --- linear: 2 passes of 64 nodes; thread owns cols (c0,c0+1), 16 nodes ---
    // slot q maps to dim k(q) = (q<64) ? 2q : 2(q-64)+1 ; consecutive q -> k += 2
    const int ch = t & 127;             // col-pair index 0..127
    const int g  = t >> 7;              // 0..3 -> node sub-group
    const int c0 = ch * 2;
    const float b0 = b[c0], b1 = b[c0 + 1];

    for (int pass = 0; pass < 2; ++pass) {
        const int nbase = pass * 64 + g * 16;   // 16 nodes for this thread

        float2 acc[16];
        #pragma unroll
        for (int i = 0; i < 16; i++) acc[i] = make_float2(0.f, 0.f);

        const float* hbase = agg + nbase * D_IN;
        for (int qb = 0; qb < D_IN; qb += 4) {
            int kb = (qb < 64) ? (qb << 1) : (((qb - 64) << 1) | 1);
            float2 w0 = *(const float2*)(W + (size_t)(kb    ) * D_OUT + c0);
            float2 w1 = *(const float2*)(W + (size_t)(kb + 2) * D_OUT + c0);
            float2 w2 = *(const float2*)(W + (size_t)(kb + 4) * D_OUT + c0);
            float2 w3 = *(const float2*)(W + (size_t)(kb + 6) * D_OUT + c0);
            #pragma unroll
            for (int i = 0; i < 16; i++) {
                float4 hv = *(const float4*)(hbase + i * D_IN + qb);
                acc[i].x += hv.x * w0.x + hv.y * w1.x + hv.z * w2.x + hv.w * w3.x;
                acc[i].y += hv.x * w0.y + hv.y * w1.y + hv.z * w2.y + hv.w * w3.y;
            }
        }

        #pragma unroll
        for (int i = 0; i < 16; i++) {
            int node = n0 + nbase + i;
            if (node < N_NODES)
                ((float2*)(out + (size_t)node * D_OUT))[ch] =
                    make_float2(acc[i].x + b0, acc[i].y + b1);
        }
    }
}

extern "C" void kernel_launch(void* const* d_in, const int* in_sizes, int n_in,
                              void* d_out, int out_size, void* d_ws, size_t ws_size,
                              hipStream_t stream)
{
    const float* x  = (const float*)d_in[0];
    const int*   ei = (const int*)d_in[1];   // [2,E] int32: row0=src, row1=dst
    const float* W  = (const float*)d_in[2];
    const float* b  = (const float*)d_in[3];
    float*       out = (float*)d_out;

    const int E = in_sizes[1] / 2;
    const int* src = ei;
    const int* dst = ei + E;
    const int chunk = (E + NBLK - 1) / NBLK;

    const size_t xb_bytes = (size_t)N_NODES * D_IN * 2;     // 25.6 MB
    const size_t pairs_b  = (size_t)E * 4;                  // 12.8 MB
    const size_t bh_b     = (size_t)NBLK * NBKT * 4;        // 1 MB
    const size_t small_b  = (size_t)NBKT * 4;               // 4 KB each
    const size_t need_bf16 = xb_bytes + pairs_b + bh_b + 2 * small_b;
    const bool use_bf16 = (ws_size >= need_bf16);

    char* p = (char*)d_ws;
    ushort* xb = nullptr;
    if (use_bf16) { xb = (ushort*)p; p += xb_bytes; }
    unsigned* pairs  = (unsigned*)p;  p += pairs_b;
    int* blockHist   = (int*)p;       p += bh_b;
    int* bucketTotal = (int*)p;       p += small_b;
    int* bucketBase  = (int*)p;

    if (use_bf16) {
        int n4 = N_NODES * D_IN / 4;
        convert_kernel<<<dim3((n4 + 255) / 256), dim3(256), 0, stream>>>(x, xb, n4);
    }

    binA_hist    <<<dim3(NBLK), dim3(256), 0, stream>>>(dst, blockHist, E, chunk);
    binA_scan    <<<dim3(NBKT), dim3(256), 0, stream>>>(blockHist, bucketTotal);
    binA_scanbase<<<dim3(1),    dim3(256), 0, stream>>>(bucketTotal, bucketBase);
    binA_scatter <<<dim3(NBLK), dim3(256), 0, stream>>>(
        src, dst, blockHist, bucketBase, pairs, E, chunk);

    if (use_bf16)
        fused_bucket<true><<<dim3(NBUCKETS), dim3(512), 0, stream>>>(
            x, xb, pairs, bucketBase, W, b, out);
    else
        fused_bucket<false><<<dim3(NBUCKETS), dim3(512), 0, stream>>>(
            x, xb, pairs, bucketBase, W, b, out);
}

// Round 4
// 518.611 us; speedup vs baseline: 7.0060x; 5.7446x over previous
//
#include <hip/hip_runtime.h>

#define N_NODES 100000
#define D_IN 128
#define D_OUT 256            // OUT_CH * HEADS
#define NBLK 256             // coarse-pass blocks
#define NBKT 1024            // bucket array size (782 used)
#define BSH  7               // bucket = dst >> 7  (128 nodes / bucket)
#define BNODES 128
#define NBUCKETS ((N_NODES + BNODES - 1) / BNODES)   // 782
#define CAP  6144            // max edges per bucket staged in LDS (mean 4096, +32 sigma)

__device__ inline unsigned short f2bf_rne(float f) {
    unsigned u = __float_as_uint(f);
    u += 0x7fffu + ((u >> 16) & 1u);
    return (unsigned short)(u >> 16);
}

// ---------------------------------------------------------------------------
// x (fp32) -> xb (bf16 as ushort)
// ---------------------------------------------------------------------------
__global__ __launch_bounds__(256) void convert_kernel(
    const float* __restrict__ x, ushort* __restrict__ xb, int n4)
{
    int i = blockIdx.x * 256 + threadIdx.x;
    if (i < n4) {
        float4 v = ((const float4*)x)[i];
        ushort4 r;
        r.x = f2bf_rne(v.x); r.y = f2bf_rne(v.y);
        r.z = f2bf_rne(v.z); r.w = f2bf_rne(v.w);
        ((ushort4*)xb)[i] = r;
    }
}

// ---------------------------------------------------------------------------
// Coarse pass 1: per-block LDS histogram of buckets
// ---------------------------------------------------------------------------
__global__ __launch_bounds__(256) void binA_hist(
    const int* __restrict__ dst, int* __restrict__ blockHist, int E, int chunk)
{
    __shared__ int h[NBKT];
    int b = blockIdx.x, t = threadIdx.x;
    for (int i = t; i < NBKT; i += 256) h[i] = 0;
    __syncthreads();
    int e0 = b * chunk, e1 = min(e0 + chunk, E);
    for (int e = e0 + t; e < e1; e += 256)
        atomicAdd(&h[dst[e] >> BSH], 1);
    __syncthreads();
    for (int i = t; i < NBKT; i += 256)
        blockHist[b * NBKT + i] = h[i];
}

// ---------------------------------------------------------------------------
// Coarse pass 2a: per-bucket exclusive scan over blocks, in place;
// bucketTotal[bucket] = column sum.  (NBLK must be <= 256)
// ---------------------------------------------------------------------------
__global__ __launch_bounds__(256) void binA_scan(
    int* __restrict__ blockHist, int* __restrict__ bucketTotal)
{
    __shared__ int wsum[4];
    int bucket = blockIdx.x;
    int t = threadIdx.x, lane = t & 63, w = t >> 6;
    int v = (t < NBLK) ? blockHist[t * NBKT + bucket] : 0;
    int s = v;
    #pragma unroll
    for (int d = 1; d < 64; d <<= 1) {
        int u = __shfl_up(s, d);
        if (lane >= d) s += u;
    }
    if (lane == 63) wsum[w] = s;
    __syncthreads();
    int wo = 0;
    for (int j = 0; j < w; j++) wo += wsum[j];
    if (t < NBLK) blockHist[t * NBKT + bucket] = wo + s - v;
    if (t == 255) {
        int tot = 0;
        for (int j = 0; j < 4; j++) tot += wsum[j];
        bucketTotal[bucket] = tot;
    }
}

// ---------------------------------------------------------------------------
// Coarse pass 2b: exclusive scan of bucketTotal[1024] -> bucketBase[1024]
// (4 entries per thread)
// ---------------------------------------------------------------------------
__global__ __launch_bounds__(256) void binA_scanbase(
    const int* __restrict__ bucketTotal, int* __restrict__ bucketBase)
{
    __shared__ int wsum[4];
    int t = threadIdx.x, lane = t & 63, w = t >> 6;
    int i0 = t * 4;
    int a0 = bucketTotal[i0];
    int a1 = bucketTotal[i0 + 1];
    int a2 = bucketTotal[i0 + 2];
    int a3 = bucketTotal[i0 + 3];
    int v = a0 + a1 + a2 + a3;
    int s = v;
    #pragma unroll
    for (int d = 1; d < 64; d <<= 1) {
        int u = __shfl_up(s, d);
        if (lane >= d) s += u;
    }
    if (lane == 63) wsum[w] = s;
    __syncthreads();
    int wo = 0;
    for (int j = 0; j < w; j++) wo += wsum[j];
    int excl = wo + s - v;
    bucketBase[i0]     = excl;
    bucketBase[i0 + 1] = excl + a0;
    bucketBase[i0 + 2] = excl + a0 + a1;
    bucketBase[i0 + 3] = excl + a0 + a1 + a2;
}

// ---------------------------------------------------------------------------
// Coarse pass 3: scatter packed (dstLocal<<17 | src) into bucket regions.
// ---------------------------------------------------------------------------
__global__ __launch_bounds__(256) void binA_scatter(
    const int* __restrict__ src, const int* __restrict__ dst,
    const int* __restrict__ blockHist, const int* __restrict__ bucketBase,
    unsigned* __restrict__ pairs, int E, int chunk)
{
    __shared__ int offs[NBKT];
    int b = blockIdx.x, t = threadIdx.x;
    for (int i = t; i < NBKT; i += 256)
        offs[i] = bucketBase[i] + blockHist[b * NBKT + i];
    __syncthreads();
    int e0 = b * chunk, e1 = min(e0 + chunk, E);
    for (int e = e0 + t; e < e1; e += 256) {
        int d = dst[e];
        int bin = d >> BSH;
        int pos = atomicAdd(&offs[bin], 1);
        pairs[pos] = ((unsigned)(d & (BNODES - 1)) << 17) | (unsigned)src[e];
    }
}

// ---------------------------------------------------------------------------
// Fine pass: per-bucket LDS counting sort (128-node buckets, 24 KB stage).
// Stages bucket edges in LDS, builds per-node deg/offs, rewrites sorted src
// IN PLACE over pairs.
// ---------------------------------------------------------------------------
__global__ __launch_bounds__(256) void binB_sort(
    unsigned* __restrict__ pairs, const int* __restrict__ bucketBase,
    int* __restrict__ offs_g, int* __restrict__ deg_g)
{
    __shared__ unsigned stage[CAP];
    __shared__ int hist[256];
    __shared__ int rank[256];
    __shared__ int wsum[4];

    int b = blockIdx.x, t = threadIdx.x, lane = t & 63, w = t >> 6;
    int e0 = bucketBase[b], e1 = bucketBase[b + 1];
    int cnt = e1 - e0;
    if (cnt > CAP) cnt = CAP;   // statistically unreachable (mean+32 sigma)

    hist[t] = 0;
    __syncthreads();

    for (int i = t; i < cnt; i += 256) {
        unsigned p = pairs[e0 + i];
        stage[i] = p;
        atomicAdd(&hist[p >> 17], 1);
    }
    __syncthreads();

    int v = hist[t];
    int s = v;
    #pragma unroll
    for (int d = 1; d < 64; d <<= 1) {
        int u = __shfl_up(s, d);
        if (lane >= d) s += u;
    }
    if (lane == 63) wsum[w] = s;
    __syncthreads();
    int wo = 0;
    for (int j = 0; j < w; j++) wo += wsum[j];
    int excl = wo + s - v;

    int node = (b << BSH) + t;
    if (t < BNODES && node < N_NODES) {
        offs_g[node] = e0 + excl;
        deg_g[node]  = v;
    }
    rank[t] = excl;
    __syncthreads();

    for (int i = t; i < cnt; i += 256) {
        unsigned p = stage[i];
        int pos = atomicAdd(&rank[p >> 17], 1);
        pairs[e0 + pos] = p & 0x1FFFFu;
    }
}

// ---------------------------------------------------------------------------
// Fused gather-aggregate + linear.
// Gather: readlane -> SGPR row base (scalar addressing, no per-lane 64-bit
// address math). Matmul: sh read as float4 (ds_read_b128, wave-uniform
// broadcast, conflict-free) -> half the LDS cycles of the b32 version.
// ---------------------------------------------------------------------------
template <bool USE_BF16>
__global__ __launch_bounds__(256) void fused_kernel(
    const float* __restrict__ x,
    const ushort* __restrict__ xb,
    const int* __restrict__ offs,
    const int* __restrict__ deg,
    const int* __restrict__ sorted_src,
    const float* __restrict__ W,
    const float* __restrict__ b,
    float* __restrict__ out)
{
    __shared__ __align__(16) float sh[16 * D_IN];

    int n0   = blockIdx.x * 16;
    int t    = threadIdx.x;
    int lane = t & 63;
    int w    = t >> 6;

    for (int nn = 0; nn < 4; nn++) {
        int nl = w * 4 + nn;
        int n  = n0 + nl;
        int start = offs[n];
        int d     = deg[n];
        float accx = 0.0f, accy = 0.0f;
        for (int base = 0; base < d; base += 64) {
            int m = d - base; if (m > 64) m = 64;
            int id = (lane < m) ? sorted_src[start + base + lane] : 0;
            int j = 0;
            for (; j + 4 <= m; j += 4) {
                int s0 = __builtin_amdgcn_readlane(id, j);
                int s1 = __builtin_amdgcn_readlane(id, j + 1);
                int s2 = __builtin_amdgcn_readlane(id, j + 2);
                int s3 = __builtin_amdgcn_readlane(id, j + 3);
                if (USE_BF16) {
                    ushort2 u0 = ((const ushort2*)(xb + (size_t)s0 * D_IN))[lane];
                    ushort2 u1 = ((const ushort2*)(xb + (size_t)s1 * D_IN))[lane];
                    ushort2 u2 = ((const ushort2*)(xb + (size_t)s2 * D_IN))[lane];
                    ushort2 u3 = ((const ushort2*)(xb + (size_t)s3 * D_IN))[lane];
                    accx += __uint_as_float((unsigned)u0.x << 16)
                          + __uint_as_float((unsigned)u1.x << 16)
                          + __uint_as_float((unsigned)u2.x << 16)
                          + __uint_as_float((unsigned)u3.x << 16);
                    accy += __uint_as_float((unsigned)u0.y << 16)
                          + __uint_as_float((unsigned)u1.y << 16)
                          + __uint_as_float((unsigned)u2.y << 16)
                          + __uint_as_float((unsigned)u3.y << 16);
                } else {
                    float2 v0 = ((const float2*)(x + (size_t)s0 * D_IN))[lane];
                    float2 v1 = ((const float2*)(x + (size_t)s1 * D_IN))[lane];
                    float2 v2 = ((const float2*)(x + (size_t)s2 * D_IN))[lane];
                    float2 v3 = ((const float2*)(x + (size_t)s3 * D_IN))[lane];
                    accx += v0.x + v1.x + v2.x + v3.x;
                    accy += v0.y + v1.y + v2.y + v3.y;
                }
            }
            for (; j < m; j++) {
                int s0 = __builtin_amdgcn_readlane(id, j);
                if (USE_BF16) {
                    ushort2 u0 = ((const ushort2*)(xb + (size_t)s0 * D_IN))[lane];
                    accx += __uint_as_float((unsigned)u0.x << 16);
                    accy += __uint_as_float((unsigned)u0.y << 16);
                } else {
                    float2 v0 = ((const float2*)(x + (size_t)s0 * D_IN))[lane];
                    accx += v0.x; accy += v0.y;
                }
            }
        }
        float invc = 1.0f / ((float)d + 1e-8f);
        float2 xv = ((const float2*)(x + (size_t)n * D_IN))[lane];
        float2 h;
        h.x = xv.x + accx * invc;
        h.y = xv.y + accy * invc;
        ((float2*)(sh + nl * D_IN))[lane] = h;
    }
    __syncthreads();

    float acc[16];
    #pragma unroll
    for (int i = 0; i < 16; i++) acc[i] = 0.0f;

    const int c = t;
    for (int kb = 0; kb < D_IN; kb += 4) {
        float w0 = W[(size_t)(kb + 0) * D_OUT + c];
        float w1 = W[(size_t)(kb + 1) * D_OUT + c];
        float w2 = W[(size_t)(kb + 2) * D_OUT + c];
        float w3 = W[(size_t)(kb + 3) * D_OUT + c];
        #pragma unroll
        for (int i = 0; i < 16; i++) {
            float4 hv = *(const float4*)(sh + i * D_IN + kb);
            acc[i] += hv.x * w0 + hv.y * w1 + hv.z * w2 + hv.w * w3;
        }
    }

    float bias = b[c];
    #pragma unroll
    for (int i = 0; i < 16; i++)
        out[(size_t)(n0 + i) * D_OUT + c] = acc[i] + bias;
}

extern "C" void kernel_launch(void* const* d_in, const int* in_sizes, int n_in,
                              void* d_out, int out_size, void* d_ws, size_t ws_size,
                              hipStream_t stream)
{
    const float* x  = (const float*)d_in[0];
    const int*   ei = (const int*)d_in[1];   // [2,E] int32: row0=src, row1=dst
    const float* W  = (const float*)d_in[2];
    const float* b  = (const float*)d_in[3];
    float*       out = (float*)d_out;

    const int E = in_sizes[1] / 2;
    const int* src = ei;
    const int* dst = ei + E;
    const int chunk = (E + NBLK - 1) / NBLK;

    const size_t xb_bytes   = (size_t)N_NODES * D_IN * 2;     // 25.6 MB
    const size_t pairs_b    = (size_t)E * 4;                  // 12.8 MB
    const size_t bh_b       = (size_t)NBLK * NBKT * 4;        // 1 MB
    const size_t small_b    = (size_t)NBKT * 4;               // 4 KB each
    const size_t nodes_b    = (size_t)N_NODES * 4;            // 400 KB each
    const size_t need_bf16  = xb_bytes + pairs_b + bh_b + 2 * small_b + 2 * nodes_b;
    const bool use_bf16 = (ws_size >= need_bf16);

    char* p = (char*)d_ws;
    ushort* xb = nullptr;
    if (use_bf16) { xb = (ushort*)p; p += xb_bytes; }
    unsigned* pairs  = (unsigned*)p;  p += pairs_b;
    int* blockHist   = (int*)p;       p += bh_b;
    int* bucketTotal = (int*)p;       p += small_b;
    int* bucketBase  = (int*)p;       p += small_b;
    int* offs        = (int*)p;       p += nodes_b;
    int* deg         = (int*)p;

    if (use_bf16) {
        int n4 = N_NODES * D_IN / 4;
        convert_kernel<<<dim3((n4 + 255) / 256), dim3(256), 0, stream>>>(x, xb, n4);
    }

    binA_hist    <<<dim3(NBLK), dim3(256), 0, stream>>>(dst, blockHist, E, chunk);
    binA_scan    <<<dim3(NBKT), dim3(256), 0, stream>>>(blockHist, bucketTotal);
    binA_scanbase<<<dim3(1),    dim3(256), 0, stream>>>(bucketTotal, bucketBase);
    binA_scatter <<<dim3(NBLK), dim3(256), 0, stream>>>(
        src, dst, blockHist, bucketBase, pairs, E, chunk);
    binB_sort    <<<dim3(NBUCKETS), dim3(256), 0, stream>>>(
        pairs, bucketBase, offs, deg);

    if (use_bf16)
        fused_kernel<true><<<dim3(N_NODES / 16), dim3(256), 0, stream>>>(
            x, xb, offs, deg, (const int*)pairs, W, b, out);
    else
        fused_kernel<false><<<dim3(N_NODES / 16), dim3(256), 0, stream>>>(
            x, xb, offs, deg, (const int*)pairs, W, b, out);
}

// Round 5
// 408.746 us; speedup vs baseline: 8.8891x; 1.2688x over previous
//
#include <hip/hip_runtime.h>

#define N_NODES 100000
#define D_IN 128
#define D_OUT 256            // OUT_CH * HEADS
#define NBLK 512             // coarse-pass blocks (2 rows/thread in scan)
#define NBKT 2048            // bucket array size (1563 used)
#define BSH  6               // bucket = dst >> 6  (64 nodes / bucket)
#define BNODES 64
#define NBUCKETS ((N_NODES + BNODES - 1) / BNODES)   // 1563
#define CAP  3072            // max edges per bucket in LDS (mean 2048, +22 sigma)

typedef __attribute__((ext_vector_type(8))) short short8_t;  // 8 bf16
typedef __attribute__((ext_vector_type(4))) float f32x4;

__device__ inline unsigned short f2bf_rne(float f) {
    unsigned u = __float_as_uint(f);
    u += 0x7fffu + ((u >> 16) & 1u);
    return (unsigned short)(u >> 16);
}

// ---------------------------------------------------------------------------
// x (fp32) -> xb (bf16 as ushort)
// ---------------------------------------------------------------------------
__global__ __launch_bounds__(256) void convert_kernel(
    const float* __restrict__ x, ushort* __restrict__ xb, int n4)
{
    int i = blockIdx.x * 256 + threadIdx.x;
    if (i < n4) {
        float4 v = ((const float4*)x)[i];
        ushort4 r;
        r.x = f2bf_rne(v.x); r.y = f2bf_rne(v.y);
        r.z = f2bf_rne(v.z); r.w = f2bf_rne(v.w);
        ((ushort4*)xb)[i] = r;
    }
}

// ---------------------------------------------------------------------------
// W (fp32 [128][256]) -> wfrag: MFMA B-fragment order, bf16.
// frag index fi = ks*16+nt (ks: K-step of 32, nt: 16-col tile).
// lane l, elem e  <->  B[k][n], k = ks*32 + (l>>4)*8 + e, n = nt*16 + (l&15).
// ---------------------------------------------------------------------------
__global__ __launch_bounds__(256) void wfrag_kernel(
    const float* __restrict__ W, short8_t* __restrict__ wfrag)
{
    int tid  = blockIdx.x * 256 + threadIdx.x;   // 4096 frags total
    int lane = tid & 63;
    int fi   = tid >> 6;                          // 0..63
    int ks   = fi >> 4, nt = fi & 15;
    int k0   = ks * 32 + (lane >> 4) * 8;
    int col  = nt * 16 + (lane & 15);
    short8_t v;
    #pragma unroll
    for (int e = 0; e < 8; e++)
        v[e] = (short)f2bf_rne(W[(size_t)(k0 + e) * D_OUT + col]);
    wfrag[tid] = v;
}

// ---------------------------------------------------------------------------
// Coarse pass 1: per-block LDS histogram of buckets
// ---------------------------------------------------------------------------
__global__ __launch_bounds__(256) void binA_hist(
    const int* __restrict__ dst, int* __restrict__ blockHist, int E, int chunk)
{
    __shared__ int h[NBKT];
    int b = blockIdx.x, t = threadIdx.x;
    for (int i = t; i < NBKT; i += 256) h[i] = 0;
    __syncthreads();
    int e0 = b * chunk, e1 = min(e0 + chunk, E);
    for (int e = e0 + t; e < e1; e += 256)
        atomicAdd(&h[dst[e] >> BSH], 1);
    __syncthreads();
    for (int i = t; i < NBKT; i += 256)
        blockHist[b * NBKT + i] = h[i];
}

// ---------------------------------------------------------------------------
// Coarse pass 2a: per-bucket exclusive scan over NBLK=512 blocks (2 rows per
// thread), in place; bucketTotal[bucket] = column sum.
// ---------------------------------------------------------------------------
__global__ __launch_bounds__(256) void binA_scan(
    int* __restrict__ blockHist, int* __restrict__ bucketTotal)
{
    __shared__ int wsum[4];
    int bucket = blockIdx.x;
    int t = threadIdx.x, lane = t & 63, w = t >> 6;
    int v0 = blockHist[(t * 2    ) * NBKT + bucket];
    int v1 = blockHist[(t * 2 + 1) * NBKT + bucket];
    int v = v0 + v1;
    int s = v;
    #pragma unroll
    for (int d = 1; d < 64; d <<= 1) {
        int u = __shfl_up(s, d);
        if (lane >= d) s += u;
    }
    if (lane == 63) wsum[w] = s;
    __syncthreads();
    int wo = 0;
    for (int j = 0; j < w; j++) wo += wsum[j];
    int excl = wo + s - v;
    blockHist[(t * 2    ) * NBKT + bucket] = excl;
    blockHist[(t * 2 + 1) * NBKT + bucket] = excl + v0;
    if (t == 255) {
        int tot = 0;
        for (int j = 0; j < 4; j++) tot += wsum[j];
        bucketTotal[bucket] = tot;
    }
}

// ---------------------------------------------------------------------------
// Coarse pass 2b: exclusive scan of bucketTotal[2048] -> bucketBase[2048]
// (8 entries per thread)
// ---------------------------------------------------------------------------
__global__ __launch_bounds__(256) void binA_scanbase(
    const int* __restrict__ bucketTotal, int* __restrict__ bucketBase)
{
    __shared__ int wsum[4];
    int t = threadIdx.x, lane = t & 63, w = t >> 6;
    int i0 = t * 8;
    int a[8], v = 0;
    #pragma unroll
    for (int j = 0; j < 8; j++) { a[j] = bucketTotal[i0 + j]; v += a[j]; }
    int s = v;
    #pragma unroll
    for (int d = 1; d < 64; d <<= 1) {
        int u = __shfl_up(s, d);
        if (lane >= d) s += u;
    }
    if (lane == 63) wsum[w] = s;
    __syncthreads();
    int wo = 0;
    for (int j = 0; j < w; j++) wo += wsum[j];
    int excl = wo + s - v;
    #pragma unroll
    for (int j = 0; j < 8; j++) { bucketBase[i0 + j] = excl; excl += a[j]; }
}

// ---------------------------------------------------------------------------
// Coarse pass 3: scatter packed (dstLocal<<17 | src) into bucket regions.
// ---------------------------------------------------------------------------
__global__ __launch_bounds__(256) void binA_scatter(
    const int* __restrict__ src, const int* __restrict__ dst,
    const int* __restrict__ blockHist, const int* __restrict__ bucketBase,
    unsigned* __restrict__ pairs, int E, int chunk)
{
    __shared__ int offs[NBKT];
    int b = blockIdx.x, t = threadIdx.x;
    for (int i = t; i < NBKT; i += 256)
        offs[i] = bucketBase[i] + blockHist[b * NBKT + i];
    __syncthreads();
    int e0 = b * chunk, e1 = min(e0 + chunk, E);
    for (int e = e0 + t; e < e1; e += 256) {
        int d = dst[e];
        int bin = d >> BSH;
        int pos = atomicAdd(&offs[bin], 1);
        pairs[pos] = ((unsigned)(d & (BNODES - 1)) << 17) | (unsigned)src[e];
    }
}

// ---------------------------------------------------------------------------
// Fine pass: per-bucket LDS counting sort (64-node buckets, ~14 KB LDS).
// ---------------------------------------------------------------------------
__global__ __launch_bounds__(256) void binB_sort(
    unsigned* __restrict__ pairs, const int* __restrict__ bucketBase,
    int* __restrict__ offs_g, int* __restrict__ deg_g)
{
    __shared__ unsigned stage[CAP];
    __shared__ int hist[256];
    __shared__ int rank[256];
    __shared__ int wsum[4];

    int b = blockIdx.x, t = threadIdx.x, lane = t & 63, w = t >> 6;
    int e0 = bucketBase[b], e1 = bucketBase[b + 1];
    int cnt = e1 - e0;
    if (cnt > CAP) cnt = CAP;   // statistically unreachable (mean+22 sigma)

    hist[t] = 0;
    __syncthreads();

    for (int i = t; i < cnt; i += 256) {
        unsigned p = pairs[e0 + i];
        stage[i] = p;
        atomicAdd(&hist[p >> 17], 1);
    }
    __syncthreads();

    int v = hist[t];
    int s = v;
    #pragma unroll
    for (int d = 1; d < 64; d <<= 1) {
        int u = __shfl_up(s, d);
        if (lane >= d) s += u;
    }
    if (lane == 63) wsum[w] = s;
    __syncthreads();
    int wo = 0;
    for (int j = 0; j < w; j++) wo += wsum[j];
    int excl = wo + s - v;

    int node = (b << BSH) + t;
    if (t < BNODES && node < N_NODES) {
        offs_g[node] = e0 + excl;
        deg_g[node]  = v;
    }
    rank[t] = excl;
    __syncthreads();

    for (int i = t; i < cnt; i += 256) {
        unsigned p = stage[i];
        int pos = atomicAdd(&rank[p >> 17], 1);
        pairs[e0 + pos] = p & 0x1FFFFu;
    }
}

// ---------------------------------------------------------------------------
// Fused gather-aggregate + MFMA linear.
// Gather unchanged (round-4 verified). h packed to bf16 in LDS with XOR
// swizzle (byte ^= (row&7)<<4) so MFMA A-frag ds_read_b128 is 2-way (free).
// Matmul: per block M=16 (nodes) x K=128 x N=256 via mfma_f32_16x16x32_bf16.
// Wave w owns 16-col tiles w*4..w*4+3; 16 MFMA/wave; B-frags from wfrag.
// C/D mapping (m89-verified): col = lane&15, row = (lane>>4)*4 + reg.
// ---------------------------------------------------------------------------
template <bool USE_BF16>
__global__ __launch_bounds__(256) void fused_kernel(
    const float* __restrict__ x,
    const ushort* __restrict__ xb,
    const int* __restrict__ offs,
    const int* __restrict__ deg,
    const int* __restrict__ sorted_src,
    const short8_t* __restrict__ wfrag,
    const float* __restrict__ b,
    float* __restrict__ out)
{
    __shared__ __align__(16) ushort shb[16 * D_IN];   // 4 KB bf16 h, swizzled

    int n0   = blockIdx.x * 16;
    int t    = threadIdx.x;
    int lane = t & 63;
    int w    = t >> 6;

    for (int nn = 0; nn < 4; nn++) {
        int nl = w * 4 + nn;
        int n  = n0 + nl;
        int start = offs[n];
        int d     = deg[n];
        float accx = 0.0f, accy = 0.0f;
        for (int base = 0; base < d; base += 64) {
            int m = d - base; if (m > 64) m = 64;
            int id = (lane < m) ? sorted_src[start + base + lane] : 0;
            int j = 0;
            for (; j + 4 <= m; j += 4) {
                int s0 = __builtin_amdgcn_readlane(id, j);
                int s1 = __builtin_amdgcn_readlane(id, j + 1);
                int s2 = __builtin_amdgcn_readlane(id, j + 2);
                int s3 = __builtin_amdgcn_readlane(id, j + 3);
                if (USE_BF16) {
                    ushort2 u0 = ((const ushort2*)(xb + (size_t)s0 * D_IN))[lane];
                    ushort2 u1 = ((const ushort2*)(xb + (size_t)s1 * D_IN))[lane];
                    ushort2 u2 = ((const ushort2*)(xb + (size_t)s2 * D_IN))[lane];
                    ushort2 u3 = ((const ushort2*)(xb + (size_t)s3 * D_IN))[lane];
                    accx += __uint_as_float((unsigned)u0.x << 16)
                          + __uint_as_float((unsigned)u1.x << 16)
                          + __uint_as_float((unsigned)u2.x << 16)
                          + __uint_as_float((unsigned)u3.x << 16);
                    accy += __uint_as_float((unsigned)u0.y << 16)
                          + __uint_as_float((unsigned)u1.y << 16)
                          + __uint_as_float((unsigned)u2.y << 16)
                          + __uint_as_float((unsigned)u3.y << 16);
                } else {
                    float2 v0 = ((const float2*)(x + (size_t)s0 * D_IN))[lane];
                    float2 v1 = ((const float2*)(x + (size_t)s1 * D_IN))[lane];
                    float2 v2 = ((const float2*)(x + (size_t)s2 * D_IN))[lane];
                    float2 v3 = ((const float2*)(x + (size_t)s3 * D_IN))[lane];
                    accx += v0.x + v1.x + v2.x + v3.x;
                    accy += v0.y + v1.y + v2.y + v3.y;
                }
            }
            for (; j < m; j++) {
                int s0 = __builtin_amdgcn_readlane(id, j);
                if (USE_BF16) {
                    ushort2 u0 = ((const ushort2*)(xb + (size_t)s0 * D_IN))[lane];
                    accx += __uint_as_float((unsigned)u0.x << 16);
                    accy += __uint_as_float((unsigned)u0.y << 16);
                } else {
                    float2 v0 = ((const float2*)(x + (size_t)s0 * D_IN))[lane];
                    accx += v0.x; accy += v0.y;
                }
            }
        }
        float invc = 1.0f / ((float)d + 1e-8f);
        float2 xv = ((const float2*)(x + (size_t)n * D_IN))[lane];
        float hx = xv.x + accx * invc;
        float hy = xv.y + accy * invc;
        // dims (2*lane, 2*lane+1) of row nl, bf16-packed, swizzled store
        unsigned hp = ((unsigned)f2bf_rne(hy) << 16) | (unsigned)f2bf_rne(hx);
        unsigned byteoff = ((unsigned)(nl * 256 + lane * 4)) ^ (((unsigned)nl & 7u) << 4);
        *(unsigned*)((char*)shb + byteoff) = hp;
    }
    __syncthreads();

    // ---- MFMA epilogue ----
    const int r  = lane & 15;
    const int hi = lane >> 4;

    // A-frags: lane l holds h[r][ks*32 + hi*8 .. +8]  (one b128 per ks)
    short8_t afrag[4];
    #pragma unroll
    for (int ks = 0; ks < 4; ks++) {
        unsigned aoff = ((unsigned)(r * 256 + ks * 64 + hi * 16)) ^ (((unsigned)r & 7u) << 4);
        afrag[ks] = *(const short8_t*)((const char*)shb + aoff);
    }

    f32x4 zero = {0.0f, 0.0f, 0.0f, 0.0f};
    f32x4 acc0 = zero, acc1 = zero, acc2 = zero, acc3 = zero;
    const int nt0 = w * 4;
    #pragma unroll
    for (int ks = 0; ks < 4; ks++) {
        short8_t b0 = wfrag[(ks * 16 + nt0    ) * 64 + lane];
        short8_t b1 = wfrag[(ks * 16 + nt0 + 1) * 64 + lane];
        short8_t b2 = wfrag[(ks * 16 + nt0 + 2) * 64 + lane];
        short8_t b3 = wfrag[(ks * 16 + nt0 + 3) * 64 + lane];
        acc0 = __builtin_amdgcn_mfma_f32_16x16x32_bf16(afrag[ks], b0, acc0, 0, 0, 0);
        acc1 = __builtin_amdgcn_mfma_f32_16x16x32_bf16(afrag[ks], b1, acc1, 0, 0, 0);
        acc2 = __builtin_amdgcn_mfma_f32_16x16x32_bf16(afrag[ks], b2, acc2, 0, 0, 0);
        acc3 = __builtin_amdgcn_mfma_f32_16x16x32_bf16(afrag[ks], b3, acc3, 0, 0, 0);
    }

    // Store: D col = r (within tile), row m = hi*4 + reg
    #pragma unroll
    for (int nt = 0; nt < 4; nt++) {
        f32x4 a = (nt == 0) ? acc0 : (nt == 1) ? acc1 : (nt == 2) ? acc2 : acc3;
        int col = (nt0 + nt) * 16 + r;
        float bias = b[col];
        #pragma unroll
        for (int reg = 0; reg < 4; reg++) {
            int node = n0 + hi * 4 + reg;
            out[(size_t)node * D_OUT + col] = a[reg] + bias;
        }
    }
}

extern "C" void kernel_launch(void* const* d_in, const int* in_sizes, int n_in,
                              void* d_out, int out_size, void* d_ws, size_t ws_size,
                              hipStream_t stream)
{
    const float* x  = (const float*)d_in[0];
    const int*   ei = (const int*)d_in[1];   // [2,E] int32: row0=src, row1=dst
    const float* W  = (const float*)d_in[2];
    const float* b  = (const float*)d_in[3];
    float*       out = (float*)d_out;

    const int E = in_sizes[1] / 2;
    const int* src = ei;
    const int* dst = ei + E;
    const int chunk = (E + NBLK - 1) / NBLK;

    const size_t xb_bytes   = (size_t)N_NODES * D_IN * 2;     // 25.6 MB
    const size_t pairs_b    = (size_t)E * 4;                  // 12.8 MB
    const size_t bh_b       = (size_t)NBLK * NBKT * 4;        // 4 MB
    const size_t small_b    = (size_t)NBKT * 4;               // 8 KB each
    const size_t nodes_b    = (size_t)N_NODES * 4;            // 400 KB each
    const size_t wf_b       = (size_t)4096 * 16;              // 64 KB
    const size_t need_bf16  = xb_bytes + pairs_b + bh_b + 2 * small_b
                            + 2 * nodes_b + wf_b;
    const bool use_bf16 = (ws_size >= need_bf16);

    char* p = (char*)d_ws;
    ushort* xb = nullptr;
    if (use_bf16) { xb = (ushort*)p; p += xb_bytes; }
    unsigned* pairs  = (unsigned*)p;  p += pairs_b;
    int* blockHist   = (int*)p;       p += bh_b;
    int* bucketTotal = (int*)p;       p += small_b;
    int* bucketBase  = (int*)p;       p += small_b;
    int* offs        = (int*)p;       p += nodes_b;
    int* deg         = (int*)p;       p += nodes_b;
    short8_t* wfrag  = (short8_t*)p;

    if (use_bf16) {
        int n4 = N_NODES * D_IN / 4;
        convert_kernel<<<dim3((n4 + 255) / 256), dim3(256), 0, stream>>>(x, xb, n4);
    }
    wfrag_kernel<<<dim3(16), dim3(256), 0, stream>>>(W, wfrag);

    binA_hist    <<<dim3(NBLK), dim3(256), 0, stream>>>(dst, blockHist, E, chunk);
    binA_scan    <<<dim3(NBKT), dim3(256), 0, stream>>>(blockHist, bucketTotal);
    binA_scanbase<<<dim3(1),    dim3(256), 0, stream>>>(bucketTotal, bucketBase);
    binA_scatter <<<dim3(NBLK), dim3(256), 0, stream>>>(
        src, dst, blockHist, bucketBase, pairs, E, chunk);
    binB_sort    <<<dim3(NBUCKETS), dim3(256), 0, stream>>>(
        pairs, bucketBase, offs, deg);

    if (use_bf16)
        fused_kernel<true><<<dim3(N_NODES / 16), dim3(256), 0, stream>>>(
            x, xb, offs, deg, (const int*)pairs, wfrag, b, out);
    else
        fused_kernel<false><<<dim3(N_NODES / 16), dim3(256), 0, stream>>>(
            x, xb, offs, deg, (const int*)pairs, wfrag, b, out);
}